// Round 1
// baseline (272.536 us; speedup 1.0000x reference)
//
#include <hip/hip_runtime.h>

// Grouped GRU: G=64, D=16, H=8, B=64, T=512. One cell per 8 lanes.
// R7 = R6 with the n-gate bias fold fixed. Reference:
//   n = tanh(xn + b_ih_n + r * (hn + b_hh_n))   — b_hh_n is INSIDE r*(...).
// R6 folded b_hh_n additively -> error (1-r)*b_hh_n (absmax 0.32). Now b_hh_n
// stays in its own register (scaled by 2log2e) and seeds gh[2]'s second
// partial chain, so r multiplies it. r,z gates keep the full additive fold.
//
// R6 design (unchanged): (a) PINNED 8-step x-prefetch ring — R5's VGPR=132
// proved the compiler rematerialized x loads at their use, exposing ~900 cyc
// HBM latency per step. Ring slots are asm-pinned 6 bodies after their load.
// (b) packed-fp32 proj (v_pk_fma_f32). (c) gate scales pre-folded into
// weights (-log2e for r,z; +2log2e for n).
//
// R8 = R7 resubmitted unchanged: round-0 bench failed at GPU acquisition
// (no counters). Reproducing baseline + capturing VALUBusy/SQ_WAIT/occupancy
// to discriminate stall-bound (1 wave/SIMD, no latency overlap) vs
// issue-bound before choosing between {2 waves/SIMD + 4-slot ring} and
// {gate-split 16 lanes/cell}.

#define Gn 64
#define Dn 16
#define Hn 8
#define Tn 512

typedef float v2f __attribute__((ext_vector_type(2)));

__device__ __forceinline__ float rcp_fast(float v) { return __builtin_amdgcn_rcpf(v); }
__device__ __forceinline__ float exp2_fast(float v) { return __builtin_amdgcn_exp2f(v); }

#define KNL (-1.44269504088896340736f)   // -log2(e)
#define KP2 ( 2.88539008177792681472f)   // +2*log2(e)

template <int CTRL>
__device__ __forceinline__ float dppf(float v) {
    return __int_as_float(
        __builtin_amdgcn_update_dpp(0, __float_as_int(v), CTRL, 0xF, 0xF, false));
}

__global__ __attribute__((amdgpu_flat_work_group_size(64, 64),
                          amdgpu_waves_per_eu(1, 1)))
void mcgru_kernel(
    const float* __restrict__ x,     // [B, T, G*D]
    const float* __restrict__ W_ih,  // [G, 3H, D]
    const float* __restrict__ W_hh,  // [G, 3H, H]
    const float* __restrict__ b_ih,  // [G, 3H]
    const float* __restrict__ b_hh,  // [G, 3H]
    float* __restrict__ out)         // [B, T, G, H]
{
    const int tid  = blockIdx.x * blockDim.x + threadIdx.x;
    const int cell = tid >> 3;
    const int l    = tid & 7;
    const int g    = cell & (Gn - 1);
    const int b    = cell >> 6;
    const int s4   = l & 3;
    const int q    = l >> 2;

    // DPP gather order: H[k] = h[jmap[k]], jmap[k] = l ^ {0,1,2,3,7,6,5,4}[k]
    int jmap[8];
#pragma unroll
    for (int k = 0; k < 8; ++k) {
        const int hi2 = k >> 2, r = k & 3;
        jmap[k] = ((q ^ hi2) << 2) | (s4 ^ r ^ (hi2 ? 3 : 0));
    }

    const float scale[3] = {KNL, KNL, KP2};

    // ---- preload weights, pre-scaled ----
    v2f   wih[3][8];    // W_ih row pairs, scaled
    float whh[3][8];    // W_hh columns permuted to DPP order, scaled
    float bs[3];        // r,z: (b_ih+b_hh)*KNL ; n: b_ih*KP2 only
    float bhn;          // n-gate: b_hh * KP2, kept under the r-multiplication
#pragma unroll
    for (int qg = 0; qg < 3; ++qg) {
        const int row = qg * Hn + l;
        const float sc = scale[qg];
        const float4* wr = (const float4*)(W_ih + ((size_t)g * 24 + row) * Dn);
#pragma unroll
        for (int i = 0; i < 4; ++i) {
            float4 v = wr[i];
            wih[qg][2*i+0] = (v2f){v.x * sc, v.y * sc};
            wih[qg][2*i+1] = (v2f){v.z * sc, v.w * sc};
        }
        const float* hrow = W_hh + ((size_t)g * 24 + row) * Hn;
#pragma unroll
        for (int k = 0; k < 8; ++k) whh[qg][k] = hrow[jmap[k]] * sc;
        if (qg < 2) {
            bs[qg] = (b_ih[g * 24 + row] + b_hh[g * 24 + row]) * sc;  // additive fold OK
        } else {
            bs[qg] = b_ih[g * 24 + row] * sc;   // input-side bias only
            bhn    = b_hh[g * 24 + row] * sc;   // stays inside r*(...)
        }
    }
    // Pin weights: no sink/remat into the T loop.
#pragma unroll
    for (int qg = 0; qg < 3; ++qg) {
#pragma unroll
        for (int i = 0; i < 8; ++i) asm volatile("" : "+v"(wih[qg][i]));
#pragma unroll
        for (int k = 0; k < 8; ++k) asm volatile("" : "+v"(whh[qg][k]));
        asm volatile("" : "+v"(bs[qg]));
    }
    asm volatile("" : "+v"(bhn));

    const float* xp = x   + ((size_t)b * Tn * Gn + g) * Dn;
    float*       op = out + ((size_t)b * Tn * Gn + g) * Hn + l;

    auto load_x = [&](int t, v2f* xv) {
        const float4* p = (const float4*)(xp + (size_t)t * Gn * Dn);
#pragma unroll
        for (int i = 0; i < 4; ++i) {
            float4 v = p[i];
            xv[2*i+0] = (v2f){v.x, v.y};
            xv[2*i+1] = (v2f){v.z, v.w};
        }
    };
    auto proj = [&](const v2f* xv, float* gx) {
#pragma unroll
        for (int qg = 0; qg < 3; ++qg) {
            v2f acc = wih[qg][0] * xv[0];
#pragma unroll
            for (int i = 1; i < 8; ++i) acc += wih[qg][i] * xv[i];  // v_pk_fma_f32
            gx[qg] = (bs[qg] + acc.x) + acc.y;
        }
    };

    float h = 0.0f;
    auto step = [&](const float* gx, int t) {
        float H[8];
        H[0] = h;
        H[1] = dppf<0xB1>(h);     // quad_perm xor1
        H[2] = dppf<0x4E>(h);     // quad_perm xor2
        H[3] = dppf<0x1B>(h);     // quad_perm xor3
        H[4] = dppf<0x141>(H[0]); // row_half_mirror = xor7 within octet
        H[5] = dppf<0x141>(H[1]);
        H[6] = dppf<0x141>(H[2]);
        H[7] = dppf<0x141>(H[3]);

        float gh[3];
#pragma unroll
        for (int qg = 0; qg < 3; ++qg) {
            float a = fmaf(whh[qg][1], H[1], whh[qg][0] * H[0]);
            a = fmaf(whh[qg][2], H[2], a);
            a = fmaf(whh[qg][3], H[3], a);
            // n-gate: seed with bhn so r multiplies (hn + b_hh_n), per reference
            float c = (qg == 2) ? fmaf(whh[qg][4], H[4], bhn)
                                : whh[qg][4] * H[4];
            c = fmaf(whh[qg][5], H[5], c);
            c = fmaf(whh[qg][6], H[6], c);
            c = fmaf(whh[qg][7], H[7], c);
            gh[qg] = a + c;
        }
        // weights pre-scaled: r,z rows by -log2e; n rows by +2log2e
        const float r  = rcp_fast(1.0f + exp2_fast(gx[0] + gh[0]));
        const float z  = rcp_fast(1.0f + exp2_fast(gx[1] + gh[1]));
        const float zh = z * h;
        const float om = 1.0f - z;
        const float e  = exp2_fast(fmaf(r, gh[2], gx[2]));
        const float n  = fmaf(-2.0f, rcp_fast(e + 1.0f), 1.0f);  // tanh
        h = fmaf(n, om, zh);
        __builtin_nontemporal_store(h, op + (size_t)t * (Gn * Hn));
    };

    // ---- pipeline: ring of 8 steps of x; proj 2 steps ahead of step ----
    v2f   xv[8][8];     // slot j holds x for a step 8 ahead of its write body
    float gx[2][3];     // gate proj for steps s (slot s&1) and s+1

    {
        v2f t0[8], t1[8];
        load_x(0, t0);
        load_x(1, t1);
        load_x(2, xv[2]); load_x(3, xv[3]); load_x(4, xv[4]);
        load_x(5, xv[5]); load_x(6, xv[6]); load_x(7, xv[7]);
        proj(t0, gx[0]);  // gx for step 0
        proj(t1, gx[1]);  // gx for step 1
    }

    for (int t = 0; t < Tn; t += 8) {
#pragma unroll
        for (int j = 0; j < 8; ++j) {
            const int s = t + j;
            int tl = s + 8; if (tl > Tn - 1) tl = Tn - 1;
            load_x(tl, xv[j]);            // issue early: in flight 6 bodies
            step(gx[j & 1], s);           // recurrent chain for step s
            // pin slot (j+2)&7: its load was issued 6 bodies (~900+ cyc) ago,
            // so the forced vmcnt wait here is free; blocks remat.
#pragma unroll
            for (int i = 0; i < 8; ++i) asm volatile("" : "+v"(xv[(j+2)&7][i]));
            proj(xv[(j+2)&7], gx[j & 1]); // gx for step s+2
        }
    }
}

extern "C" void kernel_launch(void* const* d_in, const int* in_sizes, int n_in,
                              void* d_out, int out_size, void* d_ws, size_t ws_size,
                              hipStream_t stream) {
    const float* x    = (const float*)d_in[0];
    const float* W_ih = (const float*)d_in[1];
    const float* W_hh = (const float*)d_in[2];
    const float* b_ih = (const float*)d_in[3];
    const float* b_hh = (const float*)d_in[4];
    float* out = (float*)d_out;

    // 4096 cells * 8 lanes = 512 waves; 1 wave/block over 256 CUs.
    dim3 grid(512), block(64);
    hipLaunchKernelGGL(mcgru_kernel, grid, block, 0, stream,
                       x, W_ih, W_hh, b_ih, b_hh, out);
}